// Round 12
// baseline (203.764 us; speedup 1.0000x reference)
//
#include <hip/hip_runtime.h>

#define NA 100000
#define NE 300000
#define STEPS 4
#define NTILES (NE / 16)        // 18750 (exact)
#define ATILES (NA / 16)        // 6250  (exact)

typedef _Float16 f16;
typedef _Float16 half8 __attribute__((ext_vector_type(8)));
using f32x4 = __attribute__((ext_vector_type(4))) float;

// ---------------------------------------------------------------------------
__global__ __launch_bounds__(256) void zero_kernel(float4* __restrict__ p, int n4)
{
    int t = blockIdx.x * 256 + threadIdx.x;
    if (t < n4) p[t] = make_float4(0.f, 0.f, 0.f, 0.f);
}

// fp32 -> fp16 bulk convert (step-0 h)
__global__ __launch_bounds__(256) void conv_kernel(
    const float* __restrict__ src, f16* __restrict__ dst, int n8)
{
    int t = blockIdx.x * 256 + threadIdx.x;
    if (t >= n8) return;
    float4 a = reinterpret_cast<const float4*>(src)[2 * t];
    float4 b = reinterpret_cast<const float4*>(src)[2 * t + 1];
    half8 o;
    o[0]=(f16)a.x; o[1]=(f16)a.y; o[2]=(f16)a.z; o[3]=(f16)a.w;
    o[4]=(f16)b.x; o[5]=(f16)b.y; o[6]=(f16)b.z; o[7]=(f16)b.w;
    reinterpret_cast<half8*>(dst)[t] = o;
}

// weights -> fp16. Wbt rows PERMUTED so lane(col,kg) emits i = kg*8..kg*8+7.
__global__ __launch_bounds__(256) void prep_kernel(
    const float* __restrict__ Wb, const float* __restrict__ bb,
    const float* __restrict__ Wih, const float* __restrict__ Whh,
    f16* __restrict__ Wbt, f16* __restrict__ Wihb, f16* __restrict__ Whhb)
{
    int t = blockIdx.x * 256 + threadIdx.x;
    if (t < 17 * 32 * 32) {
        int j = t & 31, i = (t >> 5) & 31, k = t >> 10;
        float v = (k < 16) ? Wb[k * 1024 + i * 32 + j] : bb[i * 32 + j];
        int row = ((i & 4) ? 16 : 0) + ((i >> 3) << 2) + (i & 3);
        Wbt[(k * 32 + row) * 32 + j] = (f16)v;
    } else if (t < 17 * 32 * 32 + 3072) {
        int u = t - 17 * 32 * 32;
        Wihb[u] = (f16)Wih[u];
    } else if (t < 17 * 32 * 32 + 6144) {
        int u = t - 17 * 32 * 32 - 3072;
        Whhb[u] = (f16)Whh[u];
    }
}

// --------------------------- CSR build (once) ------------------------------
__global__ __launch_bounds__(256) void hist_kernel(
    const int* __restrict__ pair, int* __restrict__ cnt)
{
    int e = blockIdx.x * 256 + threadIdx.x;
    if (e < NE) atomicAdd(&cnt[reinterpret_cast<const int2*>(pair)[e].x], 1);
}

__global__ __launch_bounds__(1024) void scan1_kernel(
    const int* __restrict__ cnt, int* __restrict__ excl, int* __restrict__ bsum)
{
    __shared__ int tmp[1024];
    int g = blockIdx.x * 1024 + threadIdx.x;
    int v = (g < NA) ? cnt[g] : 0;
    tmp[threadIdx.x] = v;
    __syncthreads();
    for (int off = 1; off < 1024; off <<= 1) {
        int u = (threadIdx.x >= off) ? tmp[threadIdx.x - off] : 0;
        __syncthreads();
        tmp[threadIdx.x] += u;
        __syncthreads();
    }
    if (g < NA) excl[g] = tmp[threadIdx.x] - v;
    if (threadIdx.x == 1023) bsum[blockIdx.x] = tmp[1023];
}

__global__ __launch_bounds__(128) void scan2_kernel(int* __restrict__ bsum, int nb)
{
    __shared__ int tmp[128];
    int i = threadIdx.x;
    int v = (i < nb) ? bsum[i] : 0;
    tmp[i] = v;
    __syncthreads();
    for (int off = 1; off < 128; off <<= 1) {
        int u = (i >= off) ? tmp[i - off] : 0;
        __syncthreads();
        tmp[i] += u;
        __syncthreads();
    }
    if (i < nb) bsum[i] = tmp[i] - v;   // exclusive
}

__global__ __launch_bounds__(256) void scan3_kernel(
    const int* __restrict__ excl, const int* __restrict__ bsum,
    int* __restrict__ rowptr, int* __restrict__ next)
{
    int g = blockIdx.x * 256 + threadIdx.x;
    if (g < NA) {
        int v = excl[g] + bsum[g >> 10];
        rowptr[g] = v;
        next[g] = v;
    }
    if (g == NA) rowptr[NA] = NE;
}

// permute nbr + bond (fp32->fp16) into dst-sorted order
__global__ __launch_bounds__(256) void scatter_kernel(
    const float* __restrict__ bond, const int* __restrict__ pair,
    int* __restrict__ next, int* __restrict__ nbrp, f16* __restrict__ bondp)
{
    int e = blockIdx.x * 256 + threadIdx.x;
    if (e >= NE) return;
    int2 p = reinterpret_cast<const int2*>(pair)[e];
    int pos = atomicAdd(&next[p.x], 1);
    nbrp[pos] = p.y;
    const float4* b4 = reinterpret_cast<const float4*>(bond + (size_t)e * 16);
    float4 b0 = b4[0], b1 = b4[1], b2 = b4[2], b3 = b4[3];
    half8 o0, o1;
    o0[0]=(f16)b0.x; o0[1]=(f16)b0.y; o0[2]=(f16)b0.z; o0[3]=(f16)b0.w;
    o0[4]=(f16)b1.x; o0[5]=(f16)b1.y; o0[6]=(f16)b1.z; o0[7]=(f16)b1.w;
    o1[0]=(f16)b2.x; o1[1]=(f16)b2.y; o1[2]=(f16)b2.z; o1[3]=(f16)b2.w;
    o1[4]=(f16)b3.x; o1[5]=(f16)b3.y; o1[6]=(f16)b3.z; o1[7]=(f16)b3.w;
    half8* dst = reinterpret_cast<half8*>(bondp + (size_t)pos * 16);
    dst[0] = o0; dst[1] = o1;
}

// ---------------------------------------------------------------------------
// msg: persistent waves, W register-resident, split 2-deep pipeline:
//   index (nbrp) prefetched 2 tiles ahead; payload (hf/bond) 1 tile ahead.
// Each ~300-500cyc gather gets a full tile compute (~300cyc) of cover and the
// nbr->hf dependency spans iterations.
// ---------------------------------------------------------------------------
__global__ __launch_bounds__(256, 2) void msg_kernel(
    const f16* __restrict__ hb,              // [NA][32] fp16
    const f16* __restrict__ bondp,           // [NE][16] fp16 (sorted)
    const int* __restrict__ nbrp,            // [NE]       (sorted)
    const f16* __restrict__ Wbt,             // [17][32][32] fp16 (row-permuted)
    f16* __restrict__ msg)                   // [NE][32] fp16 (sorted)
{
    int wave = threadIdx.x >> 6;
    int lane = threadIdx.x & 63;
    int col  = lane & 15;
    int kg   = lane >> 4;

    half8 w0[17], w1[17];
#pragma unroll
    for (int s = 0; s < 17; ++s) {
        w0[s] = *reinterpret_cast<const half8*>(Wbt + (s * 32 + col) * 32 + kg * 8);
        w1[s] = *reinterpret_cast<const half8*>(Wbt + (s * 32 + 16 + col) * 32 + kg * 8);
    }

    int wid = blockIdx.x * 4 + wave;
    int nw  = gridDim.x << 2;

    int tile = wid;
    if (tile >= NTILES) return;

    // prologue: payload for tile, index for tile+nw
    int pos = tile * 16 + col;
    int nbr0 = nbrp[pos];
    half8 cA = *reinterpret_cast<const half8*>(bondp + (size_t)pos * 16);
    half8 cB = *reinterpret_cast<const half8*>(bondp + (size_t)pos * 16 + 8);
    half8 hf = *reinterpret_cast<const half8*>(hb + (size_t)nbr0 * 32 + kg * 8);

    int tileN = tile + nw;
    int nbrN = 0;
    if (tileN < NTILES) nbrN = nbrp[tileN * 16 + col];

    while (tile < NTILES) {
        // issue payload loads for tile+nw (uses prefetched index nbrN)
        half8 hf2{}, cA2{}, cB2{};
        if (tileN < NTILES) {
            int posN = tileN * 16 + col;
            cA2 = *reinterpret_cast<const half8*>(bondp + (size_t)posN * 16);
            cB2 = *reinterpret_cast<const half8*>(bondp + (size_t)posN * 16 + 8);
            hf2 = *reinterpret_cast<const half8*>(hb + (size_t)nbrN * 32 + kg * 8);
        }
        // prefetch index for tile+2*nw
        int tileNN = tileN + nw;
        int nbrNN = 0;
        if (tileNN < NTILES) nbrNN = nbrp[tileNN * 16 + col];

        f32x4 acc0 = {0.f, 0.f, 0.f, 0.f};
        f32x4 acc1 = {0.f, 0.f, 0.f, 0.f};
#pragma unroll
        for (int s = 0; s < 16; ++s) {
            f16 ch = (s < 8) ? cA[s] : cB[s - 8];
            half8 a = hf * ch;               // v_pk_mul_f16 x4
            acc0 = __builtin_amdgcn_mfma_f32_16x16x32_f16(w0[s], a, acc0, 0, 0, 0);
            acc1 = __builtin_amdgcn_mfma_f32_16x16x32_f16(w1[s], a, acc1, 0, 0, 0);
        }
        acc0 = __builtin_amdgcn_mfma_f32_16x16x32_f16(w0[16], hf, acc0, 0, 0, 0);
        acc1 = __builtin_amdgcn_mfma_f32_16x16x32_f16(w1[16], hf, acc1, 0, 0, 0);

        half8 so;   // i = kg*8 .. kg*8+7 (contiguous via Wbt row permute)
        so[0]=(f16)acc0[0]; so[1]=(f16)acc0[1]; so[2]=(f16)acc0[2]; so[3]=(f16)acc0[3];
        so[4]=(f16)acc1[0]; so[5]=(f16)acc1[1]; so[6]=(f16)acc1[2]; so[7]=(f16)acc1[3];
        *reinterpret_cast<half8*>(msg + (size_t)pos * 32 + kg * 8) = so;

        pos = tileN * 16 + col;
        tile = tileN; tileN = tileNN;
        hf = hf2; cA = cA2; cB = cB2; nbrN = nbrNN;
    }
}

// ---------------------------------------------------------------------------
// GRU via MFMA (fp16). Weight fragments + biases + hfrag loaded BEFORE the
// segment gather (independent loads fly under gather latency); gather issues
// up to 4 loads before any add. fp32 hout only at the final step.
// ---------------------------------------------------------------------------
__global__ __launch_bounds__(256) void gru_kernel(
    const f16* __restrict__ msg,              // [NE][32] fp16 (sorted)
    const int* __restrict__ rowptr,           // [NA+1]
    const f16* __restrict__ hb,               // [NA][32] fp16 (h_prev; rewritten)
    const f16* __restrict__ Wihb,             // [96][32] fp16
    const f16* __restrict__ Whhb,             // [96][32] fp16
    const float* __restrict__ bih, const float* __restrict__ bhh,
    float* __restrict__ hout, f16* __restrict__ hbf, int write_f32)
{
    int wave = threadIdx.x >> 6;
    int lane = threadIdx.x & 63;
    int tile = blockIdx.x * 4 + wave;
    if (tile >= ATILES) return;

    int base = tile * 16;
    int col  = lane & 15;
    int kg   = lane >> 4;
    int a0   = base + col;

    // independent loads first: rowptr, hfrag, all weight frags, biases
    int st = rowptr[a0], en = rowptr[a0 + 1];
    half8 hfrag = *reinterpret_cast<const half8*>(hb + (size_t)a0 * 32 + kg * 8);

    half8 wi[6], wh[6];
#pragma unroll
    for (int t = 0; t < 6; ++t) {
        wi[t] = *reinterpret_cast<const half8*>(Wihb + (size_t)(t * 16 + col) * 32 + kg * 8);
        wh[t] = *reinterpret_cast<const half8*>(Whhb + (size_t)(t * 16 + col) * 32 + kg * 8);
    }
    float br0  = bih[col]      + bhh[col];
    float bz0  = bih[32 + col] + bhh[32 + col];
    float bin0 = bih[64 + col];
    float bhn0 = bhh[64 + col];
    float br1  = bih[16 + col]      + bhh[16 + col];
    float bz1  = bih[48 + col] + bhh[48 + col];
    float bin1 = bih[80 + col];
    float bhn1 = bhh[80 + col];

    // segment gather: up to 4 loads in flight before adds
    float xs[8] = {0.f, 0.f, 0.f, 0.f, 0.f, 0.f, 0.f, 0.f};
    int p = st;
    while (p < en) {
        int n = en - p;
        half8 m0, m1, m2, m3;
        m0 = *reinterpret_cast<const half8*>(msg + (size_t)p * 32 + kg * 8);
        if (n > 1) m1 = *reinterpret_cast<const half8*>(msg + (size_t)(p + 1) * 32 + kg * 8);
        if (n > 2) m2 = *reinterpret_cast<const half8*>(msg + (size_t)(p + 2) * 32 + kg * 8);
        if (n > 3) m3 = *reinterpret_cast<const half8*>(msg + (size_t)(p + 3) * 32 + kg * 8);
#pragma unroll
        for (int j = 0; j < 8; ++j) xs[j] += (float)m0[j];
        if (n > 1) {
#pragma unroll
            for (int j = 0; j < 8; ++j) xs[j] += (float)m1[j];
        }
        if (n > 2) {
#pragma unroll
            for (int j = 0; j < 8; ++j) xs[j] += (float)m2[j];
        }
        if (n > 3) {
#pragma unroll
            for (int j = 0; j < 8; ++j) xs[j] += (float)m3[j];
        }
        p += 4;
    }
    half8 xfrag;
#pragma unroll
    for (int j = 0; j < 8; ++j) xfrag[j] = (f16)xs[j];

    f32x4 gi[6], gh[6];
#pragma unroll
    for (int t = 0; t < 6; ++t) {
        f32x4 z = {0.f, 0.f, 0.f, 0.f};
        gi[t] = __builtin_amdgcn_mfma_f32_16x16x32_f16(xfrag, wi[t], z, 0, 0, 0);
        gh[t] = __builtin_amdgcn_mfma_f32_16x16x32_f16(hfrag, wh[t], z, 0, 0, 0);
    }

#pragma unroll
    for (int hh = 0; hh < 2; ++hh) {
        float br  = hh ? br1  : br0;
        float bz  = hh ? bz1  : bz0;
        float bin = hh ? bin1 : bin0;
        float bhn = hh ? bhn1 : bhn0;
        int i = hh * 16 + col;
#pragma unroll
        for (int reg = 0; reg < 4; ++reg) {
            int a = base + kg * 4 + reg;
            float r = 1.f / (1.f + __expf(-(gi[hh][reg] + gh[hh][reg] + br)));
            float z = 1.f / (1.f + __expf(-(gi[2 + hh][reg] + gh[2 + hh][reg] + bz)));
            float n = tanhf(gi[4 + hh][reg] + bin + r * (gh[4 + hh][reg] + bhn));
            float hp = (float)hb[(size_t)a * 32 + i];
            float o  = (1.f - z) * n + z * hp;
            if (write_f32) hout[(size_t)a * 32 + i] = o;
            hbf[(size_t)a * 32 + i] = (f16)o;
        }
    }
}

extern "C" void kernel_launch(void* const* d_in, const int* in_sizes, int n_in,
                              void* d_out, int out_size, void* d_ws, size_t ws_size,
                              hipStream_t stream)
{
    const float* atom = (const float*)d_in[0];
    const float* bond = (const float*)d_in[1];
    const int*   pair = (const int*)  d_in[2];
    const float* Wb   = (const float*)d_in[3];
    const float* bb   = (const float*)d_in[4];
    const float* W_ih = (const float*)d_in[5];
    const float* W_hh = (const float*)d_in[6];
    const float* b_ih = (const float*)d_in[7];
    const float* b_hh = (const float*)d_in[8];
    float* out = (float*)d_out;

    char* w = (char*)d_ws;
    f16* msg    = (f16*)w;                       // 19,200,000 B
    f16* hbf    = (f16*)(w + 19200000);          //  6,400,000
    f16* bondp  = (f16*)(w + 25600000);          //  9,600,000
    f16* Wbt    = (f16*)(w + 35200000);          //     34,816
    f16* Wihb   = Wbt + 17 * 32 * 32;            //      6,144
    f16* Whhb   = Wihb + 96 * 32;                //      6,144
    int* rowcnt = (int*)(w + 35248000);          //    400,000
    int* excl   = (int*)(w + 35648000);          //    400,000
    int* bsum   = (int*)(w + 36048000);          //        512
    int* rowptr = (int*)(w + 36048512);          //    400,004
    int* next   = (int*)(w + 36448516);          //    400,000
    int* nbrp   = (int*)(w + 36848516);          //  1,200,000  (end ~38.0 MB)

    const int nsb = (NA + 1023) / 1024;          // 98 scan blocks

    // --- CSR build (once per launch) ---
    zero_kernel<<<(NA * 4 / 16 + 255) / 256, 256, 0, stream>>>((float4*)rowcnt, NA * 4 / 16);
    hist_kernel<<<(NE + 255) / 256, 256, 0, stream>>>(pair, rowcnt);
    scan1_kernel<<<nsb, 1024, 0, stream>>>(rowcnt, excl, bsum);
    scan2_kernel<<<1, 128, 0, stream>>>(bsum, nsb);
    scan3_kernel<<<(NA + 1 + 255) / 256, 256, 0, stream>>>(excl, bsum, rowptr, next);
    scatter_kernel<<<(NE + 255) / 256, 256, 0, stream>>>(bond, pair, next, nbrp, bondp);

    // --- weights + h to fp16 (once) ---
    prep_kernel<<<(17 * 32 * 32 + 6144 + 255) / 256, 256, 0, stream>>>(
        Wb, bb, W_ih, W_hh, Wbt, Wihb, Whhb);
    conv_kernel<<<(NA * 32 / 8 + 255) / 256, 256, 0, stream>>>(atom, hbf, NA * 32 / 8);

    const int gru_blocks = (ATILES + 3) / 4;
    for (int s = 0; s < STEPS; ++s) {
        msg_kernel<<<512, 256, 0, stream>>>(hbf, bondp, nbrp, Wbt, msg);
        gru_kernel<<<gru_blocks, 256, 0, stream>>>(msg, rowptr, hbf, Wihb, Whhb,
                                                   b_ih, b_hh, out, hbf,
                                                   (s == STEPS - 1) ? 1 : 0);
    }
}

// Round 14
// 195.309 us; speedup vs baseline: 1.0433x; 1.0433x over previous
//
#include <hip/hip_runtime.h>
#include <hip/hip_cooperative_groups.h>

namespace cg = cooperative_groups;

#define NA 100000
#define NE 300000
#define STEPS 4
#define NTILES (NE / 16)        // 18750 (exact)
#define ATILES (NA / 16)        // 6250  (exact)
#define GBLK 512                // cooperative grid: 2 blocks/CU x 256 CUs

typedef _Float16 f16;
typedef _Float16 half8 __attribute__((ext_vector_type(8)));
using f32x4 = __attribute__((ext_vector_type(4))) float;

// ---------------------------------------------------------------------------
// setup: h fp32->fp16, zero rowcnt + total, preconvert all weights to fp16.
// (rowcnt zeroing rides here; stream order guarantees completion before hist)
// ---------------------------------------------------------------------------
__global__ __launch_bounds__(256) void setup_kernel(
    const float* __restrict__ atom,
    const float* __restrict__ Wb, const float* __restrict__ bb,
    const float* __restrict__ Wih, const float* __restrict__ Whh,
    f16* __restrict__ hbf, f16* __restrict__ Wbt,
    f16* __restrict__ Wihb, f16* __restrict__ Whhb,
    int* __restrict__ rowcnt, int* __restrict__ total)
{
    int t = blockIdx.x * 256 + threadIdx.x;
    const int NH8 = NA * 32 / 8;                 // 400000
    if (t < NH8) {
        float4 a = reinterpret_cast<const float4*>(atom)[2 * t];
        float4 b = reinterpret_cast<const float4*>(atom)[2 * t + 1];
        half8 o;
        o[0]=(f16)a.x; o[1]=(f16)a.y; o[2]=(f16)a.z; o[3]=(f16)a.w;
        o[4]=(f16)b.x; o[5]=(f16)b.y; o[6]=(f16)b.z; o[7]=(f16)b.w;
        reinterpret_cast<half8*>(hbf)[t] = o;
        return;
    }
    int u = t - NH8;
    if (u < NA) {
        rowcnt[u] = 0;
        if (u == 0) *total = 0;
        return;
    }
    int v = u - NA;
    if (v < 17 * 32 * 32) {
        int j = v & 31, i = (v >> 5) & 31, k = v >> 10;
        float val = (k < 16) ? Wb[k * 1024 + i * 32 + j] : bb[i * 32 + j];
        int row = ((i & 4) ? 16 : 0) + ((i >> 3) << 2) + (i & 3);  // i = kg*8.. permute
        Wbt[(k * 32 + row) * 32 + j] = (f16)val;
    } else if (v < 17 * 32 * 32 + 3072) {
        int q = v - 17 * 32 * 32;
        Wihb[q] = (f16)Wih[q];
    } else if (v < 17 * 32 * 32 + 6144) {
        int q = v - 17 * 32 * 32 - 3072;
        Whhb[q] = (f16)Whh[q];
    }
}

__global__ __launch_bounds__(256) void hist_kernel(
    const int* __restrict__ pair, int* __restrict__ cnt)
{
    int e = blockIdx.x * 256 + threadIdx.x;
    if (e < NE) atomicAdd(&cnt[reinterpret_cast<const int2*>(pair)[e].x], 1);
}

// one-kernel segment allocation: block-local prefix + atomic base.
// Segment placement order is nondeterministic (atomics) but contiguous and
// sized by cnt — output-equivalent; gru uses start[a]..start[a]+cnt[a].
__global__ __launch_bounds__(1024) void alloc_kernel(
    const int* __restrict__ cnt, int* __restrict__ start,
    int* __restrict__ next, int* __restrict__ total)
{
    __shared__ int tmp[1024];
    __shared__ int base;
    int g = blockIdx.x * 1024 + threadIdx.x;
    int v = (g < NA) ? cnt[g] : 0;
    tmp[threadIdx.x] = v;
    __syncthreads();
    for (int off = 1; off < 1024; off <<= 1) {
        int u = (threadIdx.x >= off) ? tmp[threadIdx.x - off] : 0;
        __syncthreads();
        tmp[threadIdx.x] += u;
        __syncthreads();
    }
    if (threadIdx.x == 1023) base = atomicAdd(total, tmp[1023]);
    __syncthreads();
    if (g < NA) {
        int s = base + tmp[threadIdx.x] - v;
        start[g] = s;
        next[g] = s;
    }
}

__global__ __launch_bounds__(256) void scatter_kernel(
    const float* __restrict__ bond, const int* __restrict__ pair,
    int* __restrict__ next, int* __restrict__ nbrp, f16* __restrict__ bondp)
{
    int e = blockIdx.x * 256 + threadIdx.x;
    if (e >= NE) return;
    int2 p = reinterpret_cast<const int2*>(pair)[e];
    int pos = atomicAdd(&next[p.x], 1);
    nbrp[pos] = p.y;
    const float4* b4 = reinterpret_cast<const float4*>(bond + (size_t)e * 16);
    float4 b0 = b4[0], b1 = b4[1], b2 = b4[2], b3 = b4[3];
    half8 o0, o1;
    o0[0]=(f16)b0.x; o0[1]=(f16)b0.y; o0[2]=(f16)b0.z; o0[3]=(f16)b0.w;
    o0[4]=(f16)b1.x; o0[5]=(f16)b1.y; o0[6]=(f16)b1.z; o0[7]=(f16)b1.w;
    o1[0]=(f16)b2.x; o1[1]=(f16)b2.y; o1[2]=(f16)b2.z; o1[3]=(f16)b2.w;
    o1[4]=(f16)b3.x; o1[5]=(f16)b3.y; o1[6]=(f16)b3.z; o1[7]=(f16)b3.w;
    half8* dst = reinterpret_cast<half8*>(bondp + (size_t)pos * 16);
    dst[0] = o0; dst[1] = o1;
}

// ---------------------------------------------------------------------------
// shared phase bodies (identical arithmetic to proven r11/r12 kernels)
// ---------------------------------------------------------------------------
__device__ __forceinline__ void msg_body(
    const f16* __restrict__ h, const f16* __restrict__ bondp,
    const int* __restrict__ nbrp, const f16* __restrict__ Wbt,
    f16* __restrict__ msgb, int wid, int nw, int col, int kg)
{
    half8 w0[17], w1[17];
#pragma unroll
    for (int t = 0; t < 17; ++t) {
        w0[t] = *reinterpret_cast<const half8*>(Wbt + (t * 32 + col) * 32 + kg * 8);
        w1[t] = *reinterpret_cast<const half8*>(Wbt + (t * 32 + 16 + col) * 32 + kg * 8);
    }
    int tile = wid;
    int pos = 0;
    half8 hf{}, cA{}, cB{};
    if (tile < NTILES) {
        pos = tile * 16 + col;
        int nbr0 = nbrp[pos];
        cA = *reinterpret_cast<const half8*>(bondp + (size_t)pos * 16);
        cB = *reinterpret_cast<const half8*>(bondp + (size_t)pos * 16 + 8);
        hf = *reinterpret_cast<const half8*>(h + (size_t)nbr0 * 32 + kg * 8);
    }
    while (tile < NTILES) {
        int tile2 = tile + nw;
        int pos2 = 0;
        half8 hf2{}, cA2{}, cB2{};
        if (tile2 < NTILES) {
            pos2 = tile2 * 16 + col;
            int nbr2 = nbrp[pos2];
            cA2 = *reinterpret_cast<const half8*>(bondp + (size_t)pos2 * 16);
            cB2 = *reinterpret_cast<const half8*>(bondp + (size_t)pos2 * 16 + 8);
            hf2 = *reinterpret_cast<const half8*>(h + (size_t)nbr2 * 32 + kg * 8);
        }
        f32x4 acc0 = {0.f, 0.f, 0.f, 0.f};
        f32x4 acc1 = {0.f, 0.f, 0.f, 0.f};
#pragma unroll
        for (int t = 0; t < 16; ++t) {
            f16 ch = (t < 8) ? cA[t] : cB[t - 8];
            half8 a = hf * ch;               // v_pk_mul_f16 x4
            acc0 = __builtin_amdgcn_mfma_f32_16x16x32_f16(w0[t], a, acc0, 0, 0, 0);
            acc1 = __builtin_amdgcn_mfma_f32_16x16x32_f16(w1[t], a, acc1, 0, 0, 0);
        }
        acc0 = __builtin_amdgcn_mfma_f32_16x16x32_f16(w0[16], hf, acc0, 0, 0, 0);
        acc1 = __builtin_amdgcn_mfma_f32_16x16x32_f16(w1[16], hf, acc1, 0, 0, 0);

        half8 so;   // i = kg*8 .. kg*8+7 (contiguous via Wbt row permute)
        so[0]=(f16)acc0[0]; so[1]=(f16)acc0[1]; so[2]=(f16)acc0[2]; so[3]=(f16)acc0[3];
        so[4]=(f16)acc1[0]; so[5]=(f16)acc1[1]; so[6]=(f16)acc1[2]; so[7]=(f16)acc1[3];
        *reinterpret_cast<half8*>(msgb + (size_t)pos * 32 + kg * 8) = so;

        tile = tile2; pos = pos2; hf = hf2; cA = cA2; cB = cB2;
    }
}

__device__ __forceinline__ void gru_body(
    const f16* __restrict__ msgb, const int* __restrict__ start,
    const int* __restrict__ cnt, f16* __restrict__ h,
    const f16* __restrict__ Wihb, const f16* __restrict__ Whhb,
    const float* __restrict__ bih, const float* __restrict__ bhh,
    float* __restrict__ hout, int wf, int wid, int nw, int col, int kg)
{
    half8 wi[6], wh[6];
#pragma unroll
    for (int t = 0; t < 6; ++t) {
        wi[t] = *reinterpret_cast<const half8*>(Wihb + (size_t)(t * 16 + col) * 32 + kg * 8);
        wh[t] = *reinterpret_cast<const half8*>(Whhb + (size_t)(t * 16 + col) * 32 + kg * 8);
    }
    float br0  = bih[col]      + bhh[col];
    float bz0  = bih[32 + col] + bhh[32 + col];
    float bin0 = bih[64 + col];
    float bhn0 = bhh[64 + col];
    float br1  = bih[16 + col] + bhh[16 + col];
    float bz1  = bih[48 + col] + bhh[48 + col];
    float bin1 = bih[80 + col];
    float bhn1 = bhh[80 + col];

    for (int tile = wid; tile < ATILES; tile += nw) {
        int base = tile * 16;
        int a0   = base + col;
        int st = start[a0], en = st + cnt[a0];
        half8 hfrag = *reinterpret_cast<const half8*>(h + (size_t)a0 * 32 + kg * 8);

        float xs[8] = {0.f, 0.f, 0.f, 0.f, 0.f, 0.f, 0.f, 0.f};
        int p = st;
        while (p < en) {
            int n = en - p;
            half8 m0, m1, m2, m3;
            m0 = *reinterpret_cast<const half8*>(msgb + (size_t)p * 32 + kg * 8);
            if (n > 1) m1 = *reinterpret_cast<const half8*>(msgb + (size_t)(p + 1) * 32 + kg * 8);
            if (n > 2) m2 = *reinterpret_cast<const half8*>(msgb + (size_t)(p + 2) * 32 + kg * 8);
            if (n > 3) m3 = *reinterpret_cast<const half8*>(msgb + (size_t)(p + 3) * 32 + kg * 8);
#pragma unroll
            for (int j = 0; j < 8; ++j) xs[j] += (float)m0[j];
            if (n > 1) {
#pragma unroll
                for (int j = 0; j < 8; ++j) xs[j] += (float)m1[j];
            }
            if (n > 2) {
#pragma unroll
                for (int j = 0; j < 8; ++j) xs[j] += (float)m2[j];
            }
            if (n > 3) {
#pragma unroll
                for (int j = 0; j < 8; ++j) xs[j] += (float)m3[j];
            }
            p += 4;
        }
        half8 xfrag;
#pragma unroll
        for (int j = 0; j < 8; ++j) xfrag[j] = (f16)xs[j];

        f32x4 gi[6], gh[6];
#pragma unroll
        for (int t = 0; t < 6; ++t) {
            f32x4 z = {0.f, 0.f, 0.f, 0.f};
            gi[t] = __builtin_amdgcn_mfma_f32_16x16x32_f16(xfrag, wi[t], z, 0, 0, 0);
            gh[t] = __builtin_amdgcn_mfma_f32_16x16x32_f16(hfrag, wh[t], z, 0, 0, 0);
        }

#pragma unroll
        for (int hh = 0; hh < 2; ++hh) {
            float br  = hh ? br1  : br0;
            float bz  = hh ? bz1  : bz0;
            float bin = hh ? bin1 : bin0;
            float bhn = hh ? bhn1 : bhn0;
            int i = hh * 16 + col;
#pragma unroll
            for (int reg = 0; reg < 4; ++reg) {
                int a = base + kg * 4 + reg;
                float r = 1.f / (1.f + __expf(-(gi[hh][reg] + gh[hh][reg] + br)));
                float z = 1.f / (1.f + __expf(-(gi[2 + hh][reg] + gh[2 + hh][reg] + bz)));
                float n = tanhf(gi[4 + hh][reg] + bin + r * (gh[4 + hh][reg] + bhn));
                float hp = (float)h[(size_t)a * 32 + i];
                float o  = (1.f - z) * n + z * hp;
                if (wf) hout[(size_t)a * 32 + i] = o;
                h[(size_t)a * 32 + i] = (f16)o;
            }
        }
    }
}

// ---------------------------------------------------------------------------
// standalone kernels (fallback path — the proven r12 structure)
// ---------------------------------------------------------------------------
__global__ __launch_bounds__(256, 2) void msg_kernel(
    const f16* __restrict__ hb, const f16* __restrict__ bondp,
    const int* __restrict__ nbrp, const f16* __restrict__ Wbt,
    f16* __restrict__ msgb)
{
    int wave = threadIdx.x >> 6;
    int lane = threadIdx.x & 63;
    msg_body(hb, bondp, nbrp, Wbt, msgb,
             blockIdx.x * 4 + wave, gridDim.x << 2, lane & 15, lane >> 4);
}

__global__ __launch_bounds__(256) void gru_kernel(
    const f16* __restrict__ msgb, const int* __restrict__ start,
    const int* __restrict__ cnt, f16* __restrict__ hb,
    const f16* __restrict__ Wihb, const f16* __restrict__ Whhb,
    const float* __restrict__ bih, const float* __restrict__ bhh,
    float* __restrict__ hout, int wf)
{
    int wave = threadIdx.x >> 6;
    int lane = threadIdx.x & 63;
    gru_body(msgb, start, cnt, hb, Wihb, Whhb, bih, bhh, hout, wf,
             blockIdx.x * 4 + wave, gridDim.x << 2, lane & 15, lane >> 4);
}

// ---------------------------------------------------------------------------
// fused 4-step cooperative kernel
// ---------------------------------------------------------------------------
__global__ __launch_bounds__(256, 2) void step_kernel(
    f16* __restrict__ h, const f16* __restrict__ bondp,
    const int* __restrict__ nbrp, const f16* __restrict__ Wbt,
    f16* __restrict__ msgb, const int* __restrict__ start,
    const int* __restrict__ cnt,
    const f16* __restrict__ Wihb, const f16* __restrict__ Whhb,
    const float* __restrict__ bih, const float* __restrict__ bhh,
    float* __restrict__ hout)
{
    cg::grid_group grid = cg::this_grid();
    int wave = threadIdx.x >> 6;
    int lane = threadIdx.x & 63;
    int col  = lane & 15;
    int kg   = lane >> 4;
    int wid  = blockIdx.x * 4 + wave;
    int nw   = gridDim.x << 2;

    for (int s = 0; s < STEPS; ++s) {
        msg_body(h, bondp, nbrp, Wbt, msgb, wid, nw, col, kg);
        grid.sync();
        gru_body(msgb, start, cnt, h, Wihb, Whhb, bih, bhh, hout,
                 (s == STEPS - 1) ? 1 : 0, wid, nw, col, kg);
        grid.sync();
    }
}

extern "C" void kernel_launch(void* const* d_in, const int* in_sizes, int n_in,
                              void* d_out, int out_size, void* d_ws, size_t ws_size,
                              hipStream_t stream)
{
    const float* atom = (const float*)d_in[0];
    const float* bond = (const float*)d_in[1];
    const int*   pair = (const int*)  d_in[2];
    const float* Wb   = (const float*)d_in[3];
    const float* bb   = (const float*)d_in[4];
    const float* W_ih = (const float*)d_in[5];
    const float* W_hh = (const float*)d_in[6];
    const float* b_ih = (const float*)d_in[7];
    const float* b_hh = (const float*)d_in[8];
    float* out = (float*)d_out;

    char* w = (char*)d_ws;
    f16* msg    = (f16*)w;                       // 19,200,000 B
    f16* hbf    = (f16*)(w + 19200000);          //  6,400,000
    f16* bondp  = (f16*)(w + 25600000);          //  9,600,000
    f16* Wbt    = (f16*)(w + 35200000);          //     34,816
    f16* Wihb   = Wbt + 17 * 32 * 32;            //      6,144
    f16* Whhb   = Wihb + 96 * 32;                //      6,144
    int* rowcnt = (int*)(w + 35248000);          //    400,000
    int* startp = (int*)(w + 35648000);          //    400,000
    int* nextp  = (int*)(w + 36048000);          //    400,000
    int* nbrp   = (int*)(w + 36448000);          //  1,200,000
    int* total  = (int*)(w + 37648000);          //          4

    // --- setup + CSR build (4 launches) ---
    const int setup_threads = NA * 32 / 8 + NA + 17 * 32 * 32 + 6144;
    setup_kernel<<<(setup_threads + 255) / 256, 256, 0, stream>>>(
        atom, Wb, bb, W_ih, W_hh, hbf, Wbt, Wihb, Whhb, rowcnt, total);
    hist_kernel<<<(NE + 255) / 256, 256, 0, stream>>>(pair, rowcnt);
    alloc_kernel<<<(NA + 1023) / 1024, 1024, 0, stream>>>(rowcnt, startp, nextp, total);
    scatter_kernel<<<(NE + 255) / 256, 256, 0, stream>>>(bond, pair, nextp, nbrp, bondp);

    // --- step loop: cooperative if 512 blocks are co-residency-safe ---
    int bpc = 0;
    hipError_t qe = hipOccupancyMaxActiveBlocksPerMultiprocessor(
        &bpc, (const void*)step_kernel, 256, 0);
    if (qe == hipSuccess && bpc >= 2) {
        void* args[12];
        args[0]  = &hbf;   args[1]  = &bondp;  args[2]  = &nbrp;
        args[3]  = &Wbt;   args[4]  = &msg;    args[5]  = &startp;
        args[6]  = &rowcnt; args[7] = &Wihb;   args[8]  = &Whhb;
        args[9]  = (void*)&b_ih; args[10] = (void*)&b_hh; args[11] = &out;
        hipLaunchCooperativeKernel((void*)step_kernel, dim3(GBLK), dim3(256),
                                   args, 0, stream);
    } else {
        const int gru_blocks = (ATILES + 3) / 4;
        for (int s = 0; s < STEPS; ++s) {
            msg_kernel<<<512, 256, 0, stream>>>(hbf, bondp, nbrp, Wbt, msg);
            gru_kernel<<<gru_blocks, 256, 0, stream>>>(msg, startp, rowcnt, hbf,
                                                       Wihb, Whhb, b_ih, b_hh, out,
                                                       (s == STEPS - 1) ? 1 : 0);
        }
    }
}